// Round 1
// baseline (172.838 us; speedup 1.0000x reference)
//
#include <hip/hip_runtime.h>

#define N_NODES 100000
#define N_EDGES 1600000
#define NCLS 40
#define BIN_SH 8
#define BIN_N 256                      // nodes per bin == block size
#define NBIN ((N_NODES + BIN_N - 1) / BIN_N)   // 391
#define BINCAP 4800                    // per-bin capacity (mean 4092 + ~11 sigma)
#define BKBLK 256                      // k_bucket blocks (1 per CU)
#define BKTHR 1024                     // k_bucket threads (16 waves/CU)
#define CHUNK (N_EDGES / BKBLK)        // 6250 edges per block

typedef __attribute__((ext_vector_type(8))) short s8v;   // 8 bf16 (4 VGPRs)
typedef __attribute__((ext_vector_type(4))) float f4v;   // MFMA C/D
typedef __attribute__((ext_vector_type(2))) unsigned int u2v;

__device__ __forceinline__ unsigned short f2bf(float f) {
    union { float f; unsigned int u; } v; v.f = f;
    unsigned int u = v.u + 0x7FFFu + ((v.u >> 16) & 1u);   // RNE
    return (unsigned short)(u >> 16);
}
__device__ __forceinline__ float blo(unsigned int u) {
    union { unsigned int u; float f; } v; v.u = u << 16; return v.f;
}
__device__ __forceinline__ float bhi(unsigned int u) {
    union { unsigned int u; float f; } v; v.u = u & 0xFFFF0000u; return v.f;
}

// ---------------- fp8 e4m3 encode/decode (HW builtins, soft fallback) -------
#if __has_builtin(__builtin_amdgcn_cvt_pk_fp8_f32) && __has_builtin(__builtin_amdgcn_cvt_f32_fp8)
#define FP8_HW 1
#else
#define FP8_HW 0
#endif

__device__ __forceinline__ unsigned char enc_e4m3_sw(float f) {
    union { float f; unsigned int u; } v; v.f = f;
    unsigned int s = (v.u >> 24) & 0x80u;
    float af = fabsf(f);
    if (af >= 448.0f) return (unsigned char)(s | 0x7E);
    if (af < 0.015625f) {
        int q = (int)rintf(af * 512.0f);
        return (unsigned char)(s | (q & 7));
    }
    unsigned int n = v.u & 0x7FFFFFFFu;
    n = n + 0x7FFFFu + ((n >> 20) & 1u);
    int e = (int)(n >> 23) - 120;
    unsigned int m = (n >> 20) & 7u;
    if (e <= 0) { int q = (int)rintf(af * 512.0f); return (unsigned char)(s | (q & 7)); }
    if (e > 15) return (unsigned char)(s | 0x7E);
    return (unsigned char)(s | (e << 3) | m);
}
__device__ __forceinline__ float dec_e4m3_sw(unsigned int byte) {
    unsigned int sgn = byte >> 7, e = (byte >> 3) & 15u, m = byte & 7u;
    float mag;
    if (e) { union { unsigned int u; float f; } v; v.u = ((e + 120u) << 23) | (m << 20); mag = v.f; }
    else mag = (float)m * 0.001953125f;
    return sgn ? -mag : mag;
}

__device__ __forceinline__ unsigned int pack4_fp8(float a, float b, float c, float d) {
#if FP8_HW
    unsigned int w = __builtin_amdgcn_cvt_pk_fp8_f32(a, b, 0u, false);
    w = __builtin_amdgcn_cvt_pk_fp8_f32(c, d, w, true);
    return w;
#else
    return (unsigned int)enc_e4m3_sw(a) | ((unsigned int)enc_e4m3_sw(b) << 8) |
           ((unsigned int)enc_e4m3_sw(c) << 16) | ((unsigned int)enc_e4m3_sw(d) << 24);
#endif
}
__device__ __forceinline__ void unpack4_fp8(unsigned int w, float& a, float& b, float& c, float& d) {
#if FP8_HW
    a = __builtin_amdgcn_cvt_f32_fp8(w, 0);
    b = __builtin_amdgcn_cvt_f32_fp8(w, 1);
    c = __builtin_amdgcn_cvt_f32_fp8(w, 2);
    d = __builtin_amdgcn_cvt_f32_fp8(w, 3);
#else
    a = dec_e4m3_sw(w & 255u); b = dec_e4m3_sw((w >> 8) & 255u);
    c = dec_e4m3_sw((w >> 16) & 255u); d = dec_e4m3_sw(w >> 24);
#endif
}

// ---------------- block-chunked bucketing into 391 x 256-node bins ----------
__global__ __launch_bounds__(BKTHR) void k_bucket(
        const int* __restrict__ srcv, const int* __restrict__ dstv,
        int* __restrict__ bcur, int* __restrict__ bedges) {
    __shared__ int cnt4[4][NBIN];
    __shared__ int base[NBIN], lcur[NBIN];
    for (int i = threadIdx.x; i < 4 * NBIN; i += BKTHR) cnt4[i / NBIN][i % NBIN] = 0;
    __syncthreads();
    const int grp = threadIdx.x >> 8;
    const int beg = blockIdx.x * CHUNK;
    const int end = beg + CHUNK;
    for (int e = beg + threadIdx.x; e < end; e += BKTHR) {
        int d = dstv[e]; d = min(max(d, 0), N_NODES - 1);
        atomicAdd(&cnt4[grp][d >> BIN_SH], 1);
    }
    __syncthreads();
    for (int i = threadIdx.x; i < NBIN; i += BKTHR) {
        int c = cnt4[0][i] + cnt4[1][i] + cnt4[2][i] + cnt4[3][i];
        base[i] = atomicAdd(&bcur[i], c);
        lcur[i] = 0;
    }
    __syncthreads();
    for (int e = beg + threadIdx.x; e < end; e += BKTHR) {
        int d = dstv[e]; d = min(max(d, 0), N_NODES - 1);
        int s = srcv[e]; s = min(max(s, 0), N_NODES - 1);
        int b = d >> BIN_SH;
        int slot = atomicAdd(&lcur[b], 1) + base[b];
        if (slot < BINCAP) bedges[b * BINCAP + slot] = ((d & (BIN_N - 1)) << 17) | s;
    }
}

// ---------------- fused CSR: histogram + scan + base-claim + fill -----------
__global__ __launch_bounds__(256) void k_csrfill(
        const int* __restrict__ bcur, const int* __restrict__ bedges,
        int* __restrict__ gcnt, uint2* __restrict__ offdeg,
        int* __restrict__ srcs) {
    __shared__ int dcnt[BIN_N];
    __shared__ int s[BIN_N];
    __shared__ int base_s;
    const int b = blockIdx.x;
    dcnt[threadIdx.x] = 0;
    __syncthreads();
    const int cnt = min(bcur[b], BINCAP);
    for (int e = threadIdx.x; e < cnt; e += 256)
        atomicAdd(&dcnt[bedges[b * BINCAP + e] >> 17], 1);
    __syncthreads();
    int v = dcnt[threadIdx.x];
    s[threadIdx.x] = v;
    __syncthreads();
    int acc = v;
    for (int off = 1; off < 256; off <<= 1) {
        int t = (threadIdx.x >= off) ? s[threadIdx.x - off] : 0;
        __syncthreads();
        acc += t;
        s[threadIdx.x] = acc;
        __syncthreads();
    }
    if (threadIdx.x == 255) base_s = atomicAdd(gcnt, acc);  // acc == bin total
    __syncthreads();
    const int gbeg = (acc - v) + base_s;
    const int node = (b << BIN_SH) + threadIdx.x;
    if (node < N_NODES) offdeg[node] = make_uint2((unsigned)gbeg, (unsigned)v);
    // reuse LDS: s -> per-node global base, dcnt -> cursor
    s[threadIdx.x] = gbeg;
    dcnt[threadIdx.x] = 0;
    __syncthreads();
    for (int e = threadIdx.x; e < cnt; e += 256) {
        int val = bedges[b * BINCAP + e];
        int dl = val >> 17;
        int sv = val & 0x1FFFF;
        int slot = atomicAdd(&dcnt[dl], 1);
        srcs[s[dl] + slot] = sv;
    }
}

// ---------------- x f32 -> bf16 cast ----------------
__global__ void k_xb(const float* __restrict__ x, unsigned int* __restrict__ xb) {
    int i = blockIdx.x * blockDim.x + threadIdx.x;
    int stride = gridDim.x * blockDim.x;
    const int total = N_NODES * 64 / 8;
    for (int t = i; t < total; t += stride) {
        float4 v0 = ((const float4*)x)[t * 2];
        float4 v1 = ((const float4*)x)[t * 2 + 1];
        uint4 o;
        o.x = (unsigned)f2bf(v0.x) | ((unsigned)f2bf(v0.y) << 16);
        o.y = (unsigned)f2bf(v0.z) | ((unsigned)f2bf(v0.w) << 16);
        o.z = (unsigned)f2bf(v1.x) | ((unsigned)f2bf(v1.y) << 16);
        o.w = (unsigned)f2bf(v1.z) | ((unsigned)f2bf(v1.w) << 16);
        ((uint4*)xb)[t] = o;
    }
}

// ---------------- gather-mean (bf16 in / bf16 out), unroll-4 ----------------
// srcs is streamed once -> non-temporal, keeps xb gather lines resident in L2.
__global__ __launch_bounds__(256) void k_agg(
        const uint2* __restrict__ offdeg, const int* __restrict__ srcs,
        const unsigned short* __restrict__ xb, unsigned short* __restrict__ aggb) {
    const int w = threadIdx.x >> 6;
    const int q = (threadIdx.x >> 4) & 3;
    const int t = threadIdx.x & 15;
    for (int node = blockIdx.x * 4 + w; node < N_NODES; node += gridDim.x * 4) {
        u2v od = __builtin_nontemporal_load((const u2v*)&offdeg[node]);
        int beg = (int)od.x;
        int end = beg + (int)od.y;
        float ax = 0.0f, ay = 0.0f, az = 0.0f, aw = 0.0f;
        int i = beg + q;
        for (; i + 12 < end; i += 16) {
            int s0 = __builtin_nontemporal_load(&srcs[i]);
            int s1 = __builtin_nontemporal_load(&srcs[i + 4]);
            int s2 = __builtin_nontemporal_load(&srcs[i + 8]);
            int s3 = __builtin_nontemporal_load(&srcs[i + 12]);
            uint2 u0 = *(const uint2*)&xb[(size_t)s0 * 64 + t * 4];
            uint2 u1 = *(const uint2*)&xb[(size_t)s1 * 64 + t * 4];
            uint2 u2 = *(const uint2*)&xb[(size_t)s2 * 64 + t * 4];
            uint2 u3 = *(const uint2*)&xb[(size_t)s3 * 64 + t * 4];
            ax += (blo(u0.x) + blo(u1.x)) + (blo(u2.x) + blo(u3.x));
            ay += (bhi(u0.x) + bhi(u1.x)) + (bhi(u2.x) + bhi(u3.x));
            az += (blo(u0.y) + blo(u1.y)) + (blo(u2.y) + blo(u3.y));
            aw += (bhi(u0.y) + bhi(u1.y)) + (bhi(u2.y) + bhi(u3.y));
        }
        for (; i + 4 < end; i += 8) {
            int s0 = __builtin_nontemporal_load(&srcs[i]);
            int s1 = __builtin_nontemporal_load(&srcs[i + 4]);
            uint2 u0 = *(const uint2*)&xb[(size_t)s0 * 64 + t * 4];
            uint2 u1 = *(const uint2*)&xb[(size_t)s1 * 64 + t * 4];
            ax += blo(u0.x) + blo(u1.x); ay += bhi(u0.x) + bhi(u1.x);
            az += blo(u0.y) + blo(u1.y); aw += bhi(u0.y) + bhi(u1.y);
        }
        if (i < end) {
            int s0 = __builtin_nontemporal_load(&srcs[i]);
            uint2 u0 = *(const uint2*)&xb[(size_t)s0 * 64 + t * 4];
            ax += blo(u0.x); ay += bhi(u0.x);
            az += blo(u0.y); aw += bhi(u0.y);
        }
        ax += __shfl_xor(ax, 16, 64); ay += __shfl_xor(ay, 16, 64);
        az += __shfl_xor(az, 16, 64); aw += __shfl_xor(aw, 16, 64);
        ax += __shfl_xor(ax, 32, 64); ay += __shfl_xor(ay, 32, 64);
        az += __shfl_xor(az, 32, 64); aw += __shfl_xor(aw, 32, 64);
        if (q == 0) {
            float rd = 1.0f / fmaxf((float)od.y, 1.0f);
            uint2 r;
            r.x = (unsigned)f2bf(ax * rd) | ((unsigned)f2bf(ay * rd) << 16);
            r.y = (unsigned)f2bf(az * rd) | ((unsigned)f2bf(aw * rd) << 16);
            *(uint2*)&aggb[(size_t)node * 64 + t * 4] = r;
        }
    }
}

// ---------------- fused dense via MFMA; h2 stored fp8 (packed 40B rows) -----
__global__ __launch_bounds__(256) void k_dense(
        const unsigned short* __restrict__ aggb, const unsigned short* __restrict__ xb,
        const float* __restrict__ W1l, const float* __restrict__ b1,
        const float* __restrict__ W1r,
        const float* __restrict__ W2l, const float* __restrict__ b2,
        const float* __restrict__ W2r,
        unsigned int* __restrict__ h2f8, float* __restrict__ op) {
    __shared__ __align__(16) unsigned short wl1[64][72], wr1[64][72];
    __shared__ __align__(16) unsigned short wl2[48][72], wr2[48][72];
    __shared__ __align__(16) unsigned short hsm[4][16][72];
    for (int idx = threadIdx.x; idx < 64 * 64; idx += 256) {
        int f = idx >> 6, k = idx & 63;
        wl1[f][k] = f2bf(W1l[idx]);
        wr1[f][k] = f2bf(W1r[idx]);
    }
    for (int idx = threadIdx.x; idx < 48 * 64; idx += 256) {
        int c = idx >> 6, k = idx & 63;
        wl2[c][k] = (c < NCLS) ? f2bf(W2l[c * 64 + k]) : (unsigned short)0;
        wr2[c][k] = (c < NCLS) ? f2bf(W2r[c * 64 + k]) : (unsigned short)0;
    }
    __syncthreads();
    const int w   = threadIdx.x >> 6;
    const int l15 = threadIdx.x & 15;
    const int g   = (threadIdx.x >> 4) & 3;
    float b1v[4][4], b2v[3][4];
    #pragma unroll
    for (int ft = 0; ft < 4; ++ft)
        #pragma unroll
        for (int r = 0; r < 4; ++r)
            b1v[ft][r] = b1[16 * ft + 4 * g + r];
    #pragma unroll
    for (int ct = 0; ct < 3; ++ct)
        #pragma unroll
        for (int r = 0; r < 4; ++r) {
            int c = 16 * ct + 4 * g + r;
            b2v[ct][r] = (c < NCLS) ? b2[c] : 0.0f;
        }
    unsigned short* hs = &hsm[w][0][0];
    const int gw = blockIdx.x * 4 + w;
    const int nw = gridDim.x * 4;
    for (int tile = gw; tile < N_NODES / 16; tile += nw) {
        const size_t node = (size_t)tile * 16 + l15;
        s8v aB0 = *(const s8v*)&aggb[node * 64 + 8 * g];
        s8v aB1 = *(const s8v*)&aggb[node * 64 + 32 + 8 * g];
        s8v xB0 = *(const s8v*)&xb[node * 64 + 8 * g];
        s8v xB1 = *(const s8v*)&xb[node * 64 + 32 + 8 * g];
        #pragma unroll
        for (int ft = 0; ft < 4; ++ft) {
            f4v c;
            c[0] = b1v[ft][0]; c[1] = b1v[ft][1]; c[2] = b1v[ft][2]; c[3] = b1v[ft][3];
            const size_t rb = (size_t)(16 * ft + l15) * 144 + 16 * g;
            s8v A0 = *(const s8v*)((const char*)wl1 + rb);
            s8v A1 = *(const s8v*)((const char*)wl1 + rb + 64);
            s8v R0 = *(const s8v*)((const char*)wr1 + rb);
            s8v R1 = *(const s8v*)((const char*)wr1 + rb + 64);
            c = __builtin_amdgcn_mfma_f32_16x16x32_bf16(A0, aB0, c, 0, 0, 0);
            c = __builtin_amdgcn_mfma_f32_16x16x32_bf16(A1, aB1, c, 0, 0, 0);
            c = __builtin_amdgcn_mfma_f32_16x16x32_bf16(R0, xB0, c, 0, 0, 0);
            c = __builtin_amdgcn_mfma_f32_16x16x32_bf16(R1, xB1, c, 0, 0, 0);
            uint2 u;
            u.x = (unsigned)f2bf(fmaxf(c[0], 0.0f)) | ((unsigned)f2bf(fmaxf(c[1], 0.0f)) << 16);
            u.y = (unsigned)f2bf(fmaxf(c[2], 0.0f)) | ((unsigned)f2bf(fmaxf(c[3], 0.0f)) << 16);
            *(uint2*)((char*)hs + l15 * 144 + 32 * ft + 8 * g) = u;
        }
        s8v hB0 = *(const s8v*)((const char*)hs + l15 * 144 + 16 * g);
        s8v hB1 = *(const s8v*)((const char*)hs + l15 * 144 + 64 + 16 * g);
        #pragma unroll
        for (int ct = 0; ct < 3; ++ct) {
            f4v p; p[0] = 0.0f; p[1] = 0.0f; p[2] = 0.0f; p[3] = 0.0f;
            f4v qv;
            qv[0] = b2v[ct][0]; qv[1] = b2v[ct][1]; qv[2] = b2v[ct][2]; qv[3] = b2v[ct][3];
            const size_t rb = (size_t)(16 * ct + l15) * 144 + 16 * g;
            s8v L0 = *(const s8v*)((const char*)wl2 + rb);
            s8v L1 = *(const s8v*)((const char*)wl2 + rb + 64);
            s8v Q0 = *(const s8v*)((const char*)wr2 + rb);
            s8v Q1 = *(const s8v*)((const char*)wr2 + rb + 64);
            p  = __builtin_amdgcn_mfma_f32_16x16x32_bf16(L0, hB0, p, 0, 0, 0);
            p  = __builtin_amdgcn_mfma_f32_16x16x32_bf16(L1, hB1, p, 0, 0, 0);
            qv = __builtin_amdgcn_mfma_f32_16x16x32_bf16(Q0, hB0, qv, 0, 0, 0);
            qv = __builtin_amdgcn_mfma_f32_16x16x32_bf16(Q1, hB1, qv, 0, 0, 0);
            int c0 = 16 * ct + 4 * g;
            if (c0 < NCLS) {
                h2f8[node * 10 + (c0 >> 2)] = pack4_fp8(p[0], p[1], p[2], p[3]);
                float4 o; o.x = qv[0]; o.y = qv[1]; o.z = qv[2]; o.w = qv[3];
                *(float4*)&op[node * NCLS + c0] = o;
            }
        }
    }
}

// ---------------- layer-2 gather: out = mean(fp8 h2[src]) + op --------------
// h2f8 packed 40B/node (4 MB total == one XCD L2); srcs/out streamed nt so
// they don't evict the gather working set. 4 independent gathers in flight.
__global__ __launch_bounds__(256) void k_out(
        const uint2* __restrict__ offdeg, const int* __restrict__ srcs,
        const unsigned int* __restrict__ h2f8, float* __restrict__ out) {
    const int w = threadIdx.x >> 6;
    const int q = (threadIdx.x >> 4) & 3;
    const int t = threadIdx.x & 15;
    for (int node = blockIdx.x * 4 + w; node < N_NODES; node += gridDim.x * 4) {
        u2v od = __builtin_nontemporal_load((const u2v*)&offdeg[node]);
        int beg = (int)od.x;
        int end = beg + (int)od.y;
        float ax = 0.0f, ay = 0.0f, az = 0.0f, aw = 0.0f;
        if (t < 10) {
            int i = beg + q;
            for (; i + 12 < end; i += 16) {
                int s0 = __builtin_nontemporal_load(&srcs[i]);
                int s1 = __builtin_nontemporal_load(&srcs[i + 4]);
                int s2 = __builtin_nontemporal_load(&srcs[i + 8]);
                int s3 = __builtin_nontemporal_load(&srcs[i + 12]);
                unsigned int u0 = h2f8[(size_t)s0 * 10 + t];
                unsigned int u1 = h2f8[(size_t)s1 * 10 + t];
                unsigned int u2 = h2f8[(size_t)s2 * 10 + t];
                unsigned int u3 = h2f8[(size_t)s3 * 10 + t];
                float a0, b0, c0, d0, a1, b1, c1, d1;
                float a2, b2, c2, d2, a3, b3, c3, d3;
                unpack4_fp8(u0, a0, b0, c0, d0);
                unpack4_fp8(u1, a1, b1, c1, d1);
                unpack4_fp8(u2, a2, b2, c2, d2);
                unpack4_fp8(u3, a3, b3, c3, d3);
                ax += (a0 + a1) + (a2 + a3); ay += (b0 + b1) + (b2 + b3);
                az += (c0 + c1) + (c2 + c3); aw += (d0 + d1) + (d2 + d3);
            }
            for (; i + 4 < end; i += 8) {
                int s0 = __builtin_nontemporal_load(&srcs[i]);
                int s1 = __builtin_nontemporal_load(&srcs[i + 4]);
                unsigned int u0 = h2f8[(size_t)s0 * 10 + t];
                unsigned int u1 = h2f8[(size_t)s1 * 10 + t];
                float a0, b0, c0, d0, a1, b1, c1, d1;
                unpack4_fp8(u0, a0, b0, c0, d0);
                unpack4_fp8(u1, a1, b1, c1, d1);
                ax += a0 + a1; ay += b0 + b1; az += c0 + c1; aw += d0 + d1;
            }
            if (i < end) {
                int s0 = __builtin_nontemporal_load(&srcs[i]);
                unsigned int u0 = h2f8[(size_t)s0 * 10 + t];
                float a0, b0, c0, d0;
                unpack4_fp8(u0, a0, b0, c0, d0);
                ax += a0; ay += b0; az += c0; aw += d0;
            }
        }
        ax += __shfl_xor(ax, 16, 64); ay += __shfl_xor(ay, 16, 64);
        az += __shfl_xor(az, 16, 64); aw += __shfl_xor(aw, 16, 64);
        ax += __shfl_xor(ax, 32, 64); ay += __shfl_xor(ay, 32, 64);
        az += __shfl_xor(az, 32, 64); aw += __shfl_xor(aw, 32, 64);
        if (q == 0 && t < 10) {
            float rd = 1.0f / fmaxf((float)od.y, 1.0f);
            f4v o = __builtin_nontemporal_load((const f4v*)&out[(size_t)node * NCLS + t * 4]);
            o.x = fmaf(ax, rd, o.x); o.y = fmaf(ay, rd, o.y);
            o.z = fmaf(az, rd, o.z); o.w = fmaf(aw, rd, o.w);
            __builtin_nontemporal_store(o, (f4v*)&out[(size_t)node * NCLS + t * 4]);
        }
    }
}

extern "C" void kernel_launch(void* const* d_in, const int* in_sizes, int n_in,
                              void* d_out, int out_size, void* d_ws, size_t ws_size,
                              hipStream_t stream) {
    const float* x   = (const float*)d_in[0];
    const int*   ei  = (const int*)d_in[1];   // [2, E] int32
    const float* W1l = (const float*)d_in[2];
    const float* b1  = (const float*)d_in[3];
    const float* W1r = (const float*)d_in[4];
    const float* W2l = (const float*)d_in[5];
    const float* b2  = (const float*)d_in[6];
    const float* W2r = (const float*)d_in[7];
    float* out = (float*)d_out;

    const int* srcv = ei;
    const int* dstv = ei + N_EDGES;

    // ws: bcur 508 | gcnt 1 | offdeg 2N | bedges NBIN*BINCAP | srcs E
    //     | aggb 64N u16 | xb 64N u16 | h2f8 10N u32 (packed 40B rows)
    int* bcur   = (int*)d_ws;              // 508 ints for bins
    int* gcnt   = bcur + 508;              // 1 int (zeroed with bcur)
    uint2* offdeg = (uint2*)(bcur + 512);
    int* bedges = (int*)(offdeg + N_NODES);
    int* srcs   = bedges + (size_t)NBIN * BINCAP;
    unsigned short* aggb = (unsigned short*)(srcs + N_EDGES);
    unsigned short* xb   = aggb + (size_t)64 * N_NODES;
    unsigned int*   h2f8 = (unsigned int*)(xb + (size_t)64 * N_NODES);

    hipMemsetAsync(bcur, 0, 512 * sizeof(int), stream);
    k_bucket<<<BKBLK, BKTHR, 0, stream>>>(srcv, dstv, bcur, bedges);
    k_xb<<<2048, 256, 0, stream>>>(x, (unsigned int*)xb);
    k_csrfill<<<NBIN, 256, 0, stream>>>(bcur, bedges, gcnt, offdeg, srcs);
    k_agg<<<2048, 256, 0, stream>>>(offdeg, srcs, xb, aggb);
    k_dense<<<768, 256, 0, stream>>>(aggb, xb, W1l, b1, W1r, W2l, b2, W2r, h2f8, out);
    k_out<<<2048, 256, 0, stream>>>(offdeg, srcs, h2f8, out);
}

// Round 2
// 165.409 us; speedup vs baseline: 1.0449x; 1.0449x over previous
//
#include <hip/hip_runtime.h>

#define N_NODES 100000
#define N_EDGES 1600000
#define NCLS 40
#define BIN_SH 8
#define BIN_N 256                      // nodes per bin == block size
#define NBIN ((N_NODES + BIN_N - 1) / BIN_N)   // 391
#define BINCAP 4800                    // per-bin capacity (mean 4092 + ~11 sigma)
#define BKBLK 256                      // k_bucket blocks (1 per CU)
#define BKTHR 1024                     // k_bucket threads (16 waves/CU)
#define CHUNK (N_EDGES / BKBLK)        // 6250 edges per block

typedef __attribute__((ext_vector_type(8))) short s8v;   // 8 bf16 (4 VGPRs)
typedef __attribute__((ext_vector_type(4))) float f4v;   // MFMA C/D
typedef __attribute__((ext_vector_type(2))) float f2v;   // packed f32 pair

__device__ __forceinline__ unsigned short f2bf(float f) {
    union { float f; unsigned int u; } v; v.f = f;
    unsigned int u = v.u + 0x7FFFu + ((v.u >> 16) & 1u);   // RNE
    return (unsigned short)(u >> 16);
}
__device__ __forceinline__ float blo(unsigned int u) {
    union { unsigned int u; float f; } v; v.u = u << 16; return v.f;
}
__device__ __forceinline__ float bhi(unsigned int u) {
    union { unsigned int u; float f; } v; v.u = u & 0xFFFF0000u; return v.f;
}

// ---------------- fp8 e4m3 encode/decode (HW builtins, soft fallback) -------
#if __has_builtin(__builtin_amdgcn_cvt_pk_fp8_f32) && __has_builtin(__builtin_amdgcn_cvt_f32_fp8)
#define FP8_HW 1
#else
#define FP8_HW 0
#endif
#if __has_builtin(__builtin_amdgcn_cvt_pk_f32_fp8)
#define FP8_PK 1
#else
#define FP8_PK 0
#endif

__device__ __forceinline__ unsigned char enc_e4m3_sw(float f) {
    union { float f; unsigned int u; } v; v.f = f;
    unsigned int s = (v.u >> 24) & 0x80u;
    float af = fabsf(f);
    if (af >= 448.0f) return (unsigned char)(s | 0x7E);
    if (af < 0.015625f) {
        int q = (int)rintf(af * 512.0f);
        return (unsigned char)(s | (q & 7));
    }
    unsigned int n = v.u & 0x7FFFFFFFu;
    n = n + 0x7FFFFu + ((n >> 20) & 1u);
    int e = (int)(n >> 23) - 120;
    unsigned int m = (n >> 20) & 7u;
    if (e <= 0) { int q = (int)rintf(af * 512.0f); return (unsigned char)(s | (q & 7)); }
    if (e > 15) return (unsigned char)(s | 0x7E);
    return (unsigned char)(s | (e << 3) | m);
}
__device__ __forceinline__ float dec_e4m3_sw(unsigned int byte) {
    unsigned int sgn = byte >> 7, e = (byte >> 3) & 15u, m = byte & 7u;
    float mag;
    if (e) { union { unsigned int u; float f; } v; v.u = ((e + 120u) << 23) | (m << 20); mag = v.f; }
    else mag = (float)m * 0.001953125f;
    return sgn ? -mag : mag;
}

__device__ __forceinline__ unsigned int pack4_fp8(float a, float b, float c, float d) {
#if FP8_HW
    unsigned int w = __builtin_amdgcn_cvt_pk_fp8_f32(a, b, 0u, false);
    w = __builtin_amdgcn_cvt_pk_fp8_f32(c, d, w, true);
    return w;
#else
    return (unsigned int)enc_e4m3_sw(a) | ((unsigned int)enc_e4m3_sw(b) << 8) |
           ((unsigned int)enc_e4m3_sw(c) << 16) | ((unsigned int)enc_e4m3_sw(d) << 24);
#endif
}

// accumulate 4 fp8 values of word u into two packed-f32 accumulators
__device__ __forceinline__ void acc_fp8(unsigned int u, f2v& lo, f2v& hi) {
#if FP8_PK
    lo += __builtin_amdgcn_cvt_pk_f32_fp8((int)u, false);   // bytes 0,1
    hi += __builtin_amdgcn_cvt_pk_f32_fp8((int)u, true);    // bytes 2,3
#else
    lo.x += dec_e4m3_sw(u & 255u);        lo.y += dec_e4m3_sw((u >> 8) & 255u);
    hi.x += dec_e4m3_sw((u >> 16) & 255u); hi.y += dec_e4m3_sw(u >> 24);
#endif
}

// ---------------- block-chunked bucketing into 391 x 256-node bins ----------
__global__ __launch_bounds__(BKTHR) void k_bucket(
        const int* __restrict__ srcv, const int* __restrict__ dstv,
        int* __restrict__ bcur, int* __restrict__ bedges) {
    __shared__ int cnt4[4][NBIN];
    __shared__ int base[NBIN], lcur[NBIN];
    for (int i = threadIdx.x; i < 4 * NBIN; i += BKTHR) cnt4[i / NBIN][i % NBIN] = 0;
    __syncthreads();
    const int grp = threadIdx.x >> 8;
    const int beg = blockIdx.x * CHUNK;
    const int end = beg + CHUNK;
    for (int e = beg + threadIdx.x; e < end; e += BKTHR) {
        int d = dstv[e]; d = min(max(d, 0), N_NODES - 1);
        atomicAdd(&cnt4[grp][d >> BIN_SH], 1);
    }
    __syncthreads();
    for (int i = threadIdx.x; i < NBIN; i += BKTHR) {
        int c = cnt4[0][i] + cnt4[1][i] + cnt4[2][i] + cnt4[3][i];
        base[i] = atomicAdd(&bcur[i], c);
        lcur[i] = 0;
    }
    __syncthreads();
    for (int e = beg + threadIdx.x; e < end; e += BKTHR) {
        int d = dstv[e]; d = min(max(d, 0), N_NODES - 1);
        int s = srcv[e]; s = min(max(s, 0), N_NODES - 1);
        int b = d >> BIN_SH;
        int slot = atomicAdd(&lcur[b], 1) + base[b];
        if (slot < BINCAP) bedges[b * BINCAP + slot] = ((d & (BIN_N - 1)) << 17) | s;
    }
}

// ---------------- fused CSR: histogram + scan + base-claim + fill -----------
__global__ __launch_bounds__(256) void k_csrfill(
        const int* __restrict__ bcur, const int* __restrict__ bedges,
        int* __restrict__ gcnt, uint2* __restrict__ offdeg,
        int* __restrict__ srcs) {
    __shared__ int dcnt[BIN_N];
    __shared__ int s[BIN_N];
    __shared__ int base_s;
    const int b = blockIdx.x;
    dcnt[threadIdx.x] = 0;
    __syncthreads();
    const int cnt = min(bcur[b], BINCAP);
    for (int e = threadIdx.x; e < cnt; e += 256)
        atomicAdd(&dcnt[bedges[b * BINCAP + e] >> 17], 1);
    __syncthreads();
    int v = dcnt[threadIdx.x];
    s[threadIdx.x] = v;
    __syncthreads();
    int acc = v;
    for (int off = 1; off < 256; off <<= 1) {
        int t = (threadIdx.x >= off) ? s[threadIdx.x - off] : 0;
        __syncthreads();
        acc += t;
        s[threadIdx.x] = acc;
        __syncthreads();
    }
    if (threadIdx.x == 255) base_s = atomicAdd(gcnt, acc);  // acc == bin total
    __syncthreads();
    const int gbeg = (acc - v) + base_s;
    const int node = (b << BIN_SH) + threadIdx.x;
    if (node < N_NODES) offdeg[node] = make_uint2((unsigned)gbeg, (unsigned)v);
    // reuse LDS: s -> per-node global base, dcnt -> cursor
    s[threadIdx.x] = gbeg;
    dcnt[threadIdx.x] = 0;
    __syncthreads();
    for (int e = threadIdx.x; e < cnt; e += 256) {
        int val = bedges[b * BINCAP + e];
        int dl = val >> 17;
        int sv = val & 0x1FFFF;
        int slot = atomicAdd(&dcnt[dl], 1);
        srcs[s[dl] + slot] = sv;
    }
}

// ---------------- x f32 -> bf16 cast ----------------
__global__ void k_xb(const float* __restrict__ x, unsigned int* __restrict__ xb) {
    int i = blockIdx.x * blockDim.x + threadIdx.x;
    int stride = gridDim.x * blockDim.x;
    const int total = N_NODES * 64 / 8;
    for (int t = i; t < total; t += stride) {
        float4 v0 = ((const float4*)x)[t * 2];
        float4 v1 = ((const float4*)x)[t * 2 + 1];
        uint4 o;
        o.x = (unsigned)f2bf(v0.x) | ((unsigned)f2bf(v0.y) << 16);
        o.y = (unsigned)f2bf(v0.z) | ((unsigned)f2bf(v0.w) << 16);
        o.z = (unsigned)f2bf(v1.x) | ((unsigned)f2bf(v1.y) << 16);
        o.w = (unsigned)f2bf(v1.z) | ((unsigned)f2bf(v1.w) << 16);
        ((uint4*)xb)[t] = o;
    }
}

// ---------------- gather-mean (bf16 in / bf16 out) --------------------------
// 2-node software pipeline: each wave aggregates two grid-strided nodes
// concurrently; the fused main loop keeps 8 independent gathers in flight.
__global__ __launch_bounds__(256) void k_agg(
        const uint2* __restrict__ offdeg, const int* __restrict__ srcs,
        const unsigned short* __restrict__ xb, unsigned short* __restrict__ aggb) {
    const int w = threadIdx.x >> 6;
    const int q = (threadIdx.x >> 4) & 3;
    const int t = threadIdx.x & 15;
    const int stride = gridDim.x * 4;
    for (int n0 = blockIdx.x * 4 + w; n0 < N_NODES; n0 += 2 * stride) {
        const int n1 = n0 + stride;
        const bool hasB = (n1 < N_NODES);
        uint2 odA = offdeg[n0];
        uint2 odB = hasB ? offdeg[n1] : make_uint2(0u, 0u);
        int iA = (int)odA.x + q, eA = (int)odA.x + (int)odA.y;
        int iB = (int)odB.x + q, eB = (int)odB.x + (int)odB.y;
        float axA = 0.0f, ayA = 0.0f, azA = 0.0f, awA = 0.0f;
        float axB = 0.0f, ayB = 0.0f, azB = 0.0f, awB = 0.0f;
        // fused main loop: 8 srcs loads + 8 gathers outstanding
        while (iA + 12 < eA && iB + 12 < eB) {
            int a0 = srcs[iA], a1 = srcs[iA + 4], a2 = srcs[iA + 8], a3 = srcs[iA + 12];
            int b0 = srcs[iB], b1 = srcs[iB + 4], b2 = srcs[iB + 8], b3 = srcs[iB + 12];
            uint2 uA0 = *(const uint2*)&xb[(size_t)a0 * 64 + t * 4];
            uint2 uA1 = *(const uint2*)&xb[(size_t)a1 * 64 + t * 4];
            uint2 uA2 = *(const uint2*)&xb[(size_t)a2 * 64 + t * 4];
            uint2 uA3 = *(const uint2*)&xb[(size_t)a3 * 64 + t * 4];
            uint2 uB0 = *(const uint2*)&xb[(size_t)b0 * 64 + t * 4];
            uint2 uB1 = *(const uint2*)&xb[(size_t)b1 * 64 + t * 4];
            uint2 uB2 = *(const uint2*)&xb[(size_t)b2 * 64 + t * 4];
            uint2 uB3 = *(const uint2*)&xb[(size_t)b3 * 64 + t * 4];
            axA += (blo(uA0.x) + blo(uA1.x)) + (blo(uA2.x) + blo(uA3.x));
            ayA += (bhi(uA0.x) + bhi(uA1.x)) + (bhi(uA2.x) + bhi(uA3.x));
            azA += (blo(uA0.y) + blo(uA1.y)) + (blo(uA2.y) + blo(uA3.y));
            awA += (bhi(uA0.y) + bhi(uA1.y)) + (bhi(uA2.y) + bhi(uA3.y));
            axB += (blo(uB0.x) + blo(uB1.x)) + (blo(uB2.x) + blo(uB3.x));
            ayB += (bhi(uB0.x) + bhi(uB1.x)) + (bhi(uB2.x) + bhi(uB3.x));
            azB += (blo(uB0.y) + blo(uB1.y)) + (blo(uB2.y) + blo(uB3.y));
            awB += (bhi(uB0.y) + bhi(uB1.y)) + (bhi(uB2.y) + bhi(uB3.y));
            iA += 16; iB += 16;
        }
        // drain A
        for (; iA + 12 < eA; iA += 16) {
            int a0 = srcs[iA], a1 = srcs[iA + 4], a2 = srcs[iA + 8], a3 = srcs[iA + 12];
            uint2 u0 = *(const uint2*)&xb[(size_t)a0 * 64 + t * 4];
            uint2 u1 = *(const uint2*)&xb[(size_t)a1 * 64 + t * 4];
            uint2 u2 = *(const uint2*)&xb[(size_t)a2 * 64 + t * 4];
            uint2 u3 = *(const uint2*)&xb[(size_t)a3 * 64 + t * 4];
            axA += (blo(u0.x) + blo(u1.x)) + (blo(u2.x) + blo(u3.x));
            ayA += (bhi(u0.x) + bhi(u1.x)) + (bhi(u2.x) + bhi(u3.x));
            azA += (blo(u0.y) + blo(u1.y)) + (blo(u2.y) + blo(u3.y));
            awA += (bhi(u0.y) + bhi(u1.y)) + (bhi(u2.y) + bhi(u3.y));
        }
        for (; iA + 4 < eA; iA += 8) {
            int a0 = srcs[iA], a1 = srcs[iA + 4];
            uint2 u0 = *(const uint2*)&xb[(size_t)a0 * 64 + t * 4];
            uint2 u1 = *(const uint2*)&xb[(size_t)a1 * 64 + t * 4];
            axA += blo(u0.x) + blo(u1.x); ayA += bhi(u0.x) + bhi(u1.x);
            azA += blo(u0.y) + blo(u1.y); awA += bhi(u0.y) + bhi(u1.y);
        }
        if (iA < eA) {
            int a0 = srcs[iA];
            uint2 u0 = *(const uint2*)&xb[(size_t)a0 * 64 + t * 4];
            axA += blo(u0.x); ayA += bhi(u0.x);
            azA += blo(u0.y); awA += bhi(u0.y);
        }
        // drain B
        for (; iB + 12 < eB; iB += 16) {
            int b0 = srcs[iB], b1 = srcs[iB + 4], b2 = srcs[iB + 8], b3 = srcs[iB + 12];
            uint2 u0 = *(const uint2*)&xb[(size_t)b0 * 64 + t * 4];
            uint2 u1 = *(const uint2*)&xb[(size_t)b1 * 64 + t * 4];
            uint2 u2 = *(const uint2*)&xb[(size_t)b2 * 64 + t * 4];
            uint2 u3 = *(const uint2*)&xb[(size_t)b3 * 64 + t * 4];
            axB += (blo(u0.x) + blo(u1.x)) + (blo(u2.x) + blo(u3.x));
            ayB += (bhi(u0.x) + bhi(u1.x)) + (bhi(u2.x) + bhi(u3.x));
            azB += (blo(u0.y) + blo(u1.y)) + (blo(u2.y) + blo(u3.y));
            awB += (bhi(u0.y) + bhi(u1.y)) + (bhi(u2.y) + bhi(u3.y));
        }
        for (; iB + 4 < eB; iB += 8) {
            int b0 = srcs[iB], b1 = srcs[iB + 4];
            uint2 u0 = *(const uint2*)&xb[(size_t)b0 * 64 + t * 4];
            uint2 u1 = *(const uint2*)&xb[(size_t)b1 * 64 + t * 4];
            axB += blo(u0.x) + blo(u1.x); ayB += bhi(u0.x) + bhi(u1.x);
            azB += blo(u0.y) + blo(u1.y); awB += bhi(u0.y) + bhi(u1.y);
        }
        if (iB < eB) {
            int b0 = srcs[iB];
            uint2 u0 = *(const uint2*)&xb[(size_t)b0 * 64 + t * 4];
            axB += blo(u0.x); ayB += bhi(u0.x);
            azB += blo(u0.y); awB += bhi(u0.y);
        }
        // cross-quarter reduction (all 64 lanes participate in shfl)
        axA += __shfl_xor(axA, 16, 64); ayA += __shfl_xor(ayA, 16, 64);
        azA += __shfl_xor(azA, 16, 64); awA += __shfl_xor(awA, 16, 64);
        axA += __shfl_xor(axA, 32, 64); ayA += __shfl_xor(ayA, 32, 64);
        azA += __shfl_xor(azA, 32, 64); awA += __shfl_xor(awA, 32, 64);
        axB += __shfl_xor(axB, 16, 64); ayB += __shfl_xor(ayB, 16, 64);
        azB += __shfl_xor(azB, 16, 64); awB += __shfl_xor(awB, 16, 64);
        axB += __shfl_xor(axB, 32, 64); ayB += __shfl_xor(ayB, 32, 64);
        azB += __shfl_xor(azB, 32, 64); awB += __shfl_xor(awB, 32, 64);
        if (q == 0) {
            float rd = 1.0f / fmaxf((float)odA.y, 1.0f);
            uint2 r;
            r.x = (unsigned)f2bf(axA * rd) | ((unsigned)f2bf(ayA * rd) << 16);
            r.y = (unsigned)f2bf(azA * rd) | ((unsigned)f2bf(awA * rd) << 16);
            *(uint2*)&aggb[(size_t)n0 * 64 + t * 4] = r;
            if (hasB) {
                float rdB = 1.0f / fmaxf((float)odB.y, 1.0f);
                uint2 rB;
                rB.x = (unsigned)f2bf(axB * rdB) | ((unsigned)f2bf(ayB * rdB) << 16);
                rB.y = (unsigned)f2bf(azB * rdB) | ((unsigned)f2bf(awB * rdB) << 16);
                *(uint2*)&aggb[(size_t)n1 * 64 + t * 4] = rB;
            }
        }
    }
}

// ---------------- fused dense via MFMA; h2 stored fp8 (64B-aligned rows) ----
__global__ __launch_bounds__(256) void k_dense(
        const unsigned short* __restrict__ aggb, const unsigned short* __restrict__ xb,
        const float* __restrict__ W1l, const float* __restrict__ b1,
        const float* __restrict__ W1r,
        const float* __restrict__ W2l, const float* __restrict__ b2,
        const float* __restrict__ W2r,
        unsigned int* __restrict__ h2f8, float* __restrict__ op) {
    __shared__ __align__(16) unsigned short wl1[64][72], wr1[64][72];
    __shared__ __align__(16) unsigned short wl2[48][72], wr2[48][72];
    __shared__ __align__(16) unsigned short hsm[4][16][72];
    for (int idx = threadIdx.x; idx < 64 * 64; idx += 256) {
        int f = idx >> 6, k = idx & 63;
        wl1[f][k] = f2bf(W1l[idx]);
        wr1[f][k] = f2bf(W1r[idx]);
    }
    for (int idx = threadIdx.x; idx < 48 * 64; idx += 256) {
        int c = idx >> 6, k = idx & 63;
        wl2[c][k] = (c < NCLS) ? f2bf(W2l[c * 64 + k]) : (unsigned short)0;
        wr2[c][k] = (c < NCLS) ? f2bf(W2r[c * 64 + k]) : (unsigned short)0;
    }
    __syncthreads();
    const int w   = threadIdx.x >> 6;
    const int l15 = threadIdx.x & 15;
    const int g   = (threadIdx.x >> 4) & 3;
    float b1v[4][4], b2v[3][4];
    #pragma unroll
    for (int ft = 0; ft < 4; ++ft)
        #pragma unroll
        for (int r = 0; r < 4; ++r)
            b1v[ft][r] = b1[16 * ft + 4 * g + r];
    #pragma unroll
    for (int ct = 0; ct < 3; ++ct)
        #pragma unroll
        for (int r = 0; r < 4; ++r) {
            int c = 16 * ct + 4 * g + r;
            b2v[ct][r] = (c < NCLS) ? b2[c] : 0.0f;
        }
    unsigned short* hs = &hsm[w][0][0];
    const int gw = blockIdx.x * 4 + w;
    const int nw = gridDim.x * 4;
    for (int tile = gw; tile < N_NODES / 16; tile += nw) {
        const size_t node = (size_t)tile * 16 + l15;
        s8v aB0 = *(const s8v*)&aggb[node * 64 + 8 * g];
        s8v aB1 = *(const s8v*)&aggb[node * 64 + 32 + 8 * g];
        s8v xB0 = *(const s8v*)&xb[node * 64 + 8 * g];
        s8v xB1 = *(const s8v*)&xb[node * 64 + 32 + 8 * g];
        #pragma unroll
        for (int ft = 0; ft < 4; ++ft) {
            f4v c;
            c[0] = b1v[ft][0]; c[1] = b1v[ft][1]; c[2] = b1v[ft][2]; c[3] = b1v[ft][3];
            const size_t rb = (size_t)(16 * ft + l15) * 144 + 16 * g;
            s8v A0 = *(const s8v*)((const char*)wl1 + rb);
            s8v A1 = *(const s8v*)((const char*)wl1 + rb + 64);
            s8v R0 = *(const s8v*)((const char*)wr1 + rb);
            s8v R1 = *(const s8v*)((const char*)wr1 + rb + 64);
            c = __builtin_amdgcn_mfma_f32_16x16x32_bf16(A0, aB0, c, 0, 0, 0);
            c = __builtin_amdgcn_mfma_f32_16x16x32_bf16(A1, aB1, c, 0, 0, 0);
            c = __builtin_amdgcn_mfma_f32_16x16x32_bf16(R0, xB0, c, 0, 0, 0);
            c = __builtin_amdgcn_mfma_f32_16x16x32_bf16(R1, xB1, c, 0, 0, 0);
            uint2 u;
            u.x = (unsigned)f2bf(fmaxf(c[0], 0.0f)) | ((unsigned)f2bf(fmaxf(c[1], 0.0f)) << 16);
            u.y = (unsigned)f2bf(fmaxf(c[2], 0.0f)) | ((unsigned)f2bf(fmaxf(c[3], 0.0f)) << 16);
            *(uint2*)((char*)hs + l15 * 144 + 32 * ft + 8 * g) = u;
        }
        s8v hB0 = *(const s8v*)((const char*)hs + l15 * 144 + 16 * g);
        s8v hB1 = *(const s8v*)((const char*)hs + l15 * 144 + 64 + 16 * g);
        #pragma unroll
        for (int ct = 0; ct < 3; ++ct) {
            f4v p; p[0] = 0.0f; p[1] = 0.0f; p[2] = 0.0f; p[3] = 0.0f;
            f4v qv;
            qv[0] = b2v[ct][0]; qv[1] = b2v[ct][1]; qv[2] = b2v[ct][2]; qv[3] = b2v[ct][3];
            const size_t rb = (size_t)(16 * ct + l15) * 144 + 16 * g;
            s8v L0 = *(const s8v*)((const char*)wl2 + rb);
            s8v L1 = *(const s8v*)((const char*)wl2 + rb + 64);
            s8v Q0 = *(const s8v*)((const char*)wr2 + rb);
            s8v Q1 = *(const s8v*)((const char*)wr2 + rb + 64);
            p  = __builtin_amdgcn_mfma_f32_16x16x32_bf16(L0, hB0, p, 0, 0, 0);
            p  = __builtin_amdgcn_mfma_f32_16x16x32_bf16(L1, hB1, p, 0, 0, 0);
            qv = __builtin_amdgcn_mfma_f32_16x16x32_bf16(Q0, hB0, qv, 0, 0, 0);
            qv = __builtin_amdgcn_mfma_f32_16x16x32_bf16(Q1, hB1, qv, 0, 0, 0);
            int c0 = 16 * ct + 4 * g;
            if (c0 < NCLS) {
                h2f8[node * 16 + (c0 >> 2)] = pack4_fp8(p[0], p[1], p[2], p[3]);
                float4 o; o.x = qv[0]; o.y = qv[1]; o.z = qv[2]; o.w = qv[3];
                *(float4*)&op[node * NCLS + c0] = o;
            }
        }
    }
}

// ---------------- layer-2 gather: out = mean(fp8 h2[src]) + op --------------
// 2-node software pipeline + packed fp8 decode (cvt_pk_f32_fp8 + v_pk_add).
__global__ __launch_bounds__(256) void k_out(
        const uint2* __restrict__ offdeg, const int* __restrict__ srcs,
        const unsigned int* __restrict__ h2f8, float* __restrict__ out) {
    const int w = threadIdx.x >> 6;
    const int q = (threadIdx.x >> 4) & 3;
    const int t = threadIdx.x & 15;
    const int stride = gridDim.x * 4;
    for (int n0 = blockIdx.x * 4 + w; n0 < N_NODES; n0 += 2 * stride) {
        const int n1 = n0 + stride;
        const bool hasB = (n1 < N_NODES);
        uint2 odA = offdeg[n0];
        uint2 odB = hasB ? offdeg[n1] : make_uint2(0u, 0u);
        int iA = (int)odA.x + q, eA = (int)odA.x + (int)odA.y;
        int iB = (int)odB.x + q, eB = (int)odB.x + (int)odB.y;
        f2v sA0 = {0.0f, 0.0f}, sA1 = {0.0f, 0.0f};
        f2v sB0 = {0.0f, 0.0f}, sB1 = {0.0f, 0.0f};
        if (t < 10) {
            // fused main loop: 8 srcs loads + 8 gathers outstanding
            while (iA + 12 < eA && iB + 12 < eB) {
                int a0 = srcs[iA], a1 = srcs[iA + 4], a2 = srcs[iA + 8], a3 = srcs[iA + 12];
                int b0 = srcs[iB], b1 = srcs[iB + 4], b2 = srcs[iB + 8], b3 = srcs[iB + 12];
                unsigned uA0 = h2f8[(size_t)a0 * 16 + t];
                unsigned uA1 = h2f8[(size_t)a1 * 16 + t];
                unsigned uA2 = h2f8[(size_t)a2 * 16 + t];
                unsigned uA3 = h2f8[(size_t)a3 * 16 + t];
                unsigned uB0 = h2f8[(size_t)b0 * 16 + t];
                unsigned uB1 = h2f8[(size_t)b1 * 16 + t];
                unsigned uB2 = h2f8[(size_t)b2 * 16 + t];
                unsigned uB3 = h2f8[(size_t)b3 * 16 + t];
                acc_fp8(uA0, sA0, sA1); acc_fp8(uA1, sA0, sA1);
                acc_fp8(uA2, sA0, sA1); acc_fp8(uA3, sA0, sA1);
                acc_fp8(uB0, sB0, sB1); acc_fp8(uB1, sB0, sB1);
                acc_fp8(uB2, sB0, sB1); acc_fp8(uB3, sB0, sB1);
                iA += 16; iB += 16;
            }
            // drain A
            for (; iA + 12 < eA; iA += 16) {
                int a0 = srcs[iA], a1 = srcs[iA + 4], a2 = srcs[iA + 8], a3 = srcs[iA + 12];
                unsigned u0 = h2f8[(size_t)a0 * 16 + t];
                unsigned u1 = h2f8[(size_t)a1 * 16 + t];
                unsigned u2 = h2f8[(size_t)a2 * 16 + t];
                unsigned u3 = h2f8[(size_t)a3 * 16 + t];
                acc_fp8(u0, sA0, sA1); acc_fp8(u1, sA0, sA1);
                acc_fp8(u2, sA0, sA1); acc_fp8(u3, sA0, sA1);
            }
            for (; iA + 4 < eA; iA += 8) {
                int a0 = srcs[iA], a1 = srcs[iA + 4];
                unsigned u0 = h2f8[(size_t)a0 * 16 + t];
                unsigned u1 = h2f8[(size_t)a1 * 16 + t];
                acc_fp8(u0, sA0, sA1); acc_fp8(u1, sA0, sA1);
            }
            if (iA < eA) {
                unsigned u0 = h2f8[(size_t)srcs[iA] * 16 + t];
                acc_fp8(u0, sA0, sA1);
            }
            // drain B
            for (; iB + 12 < eB; iB += 16) {
                int b0 = srcs[iB], b1 = srcs[iB + 4], b2 = srcs[iB + 8], b3 = srcs[iB + 12];
                unsigned u0 = h2f8[(size_t)b0 * 16 + t];
                unsigned u1 = h2f8[(size_t)b1 * 16 + t];
                unsigned u2 = h2f8[(size_t)b2 * 16 + t];
                unsigned u3 = h2f8[(size_t)b3 * 16 + t];
                acc_fp8(u0, sB0, sB1); acc_fp8(u1, sB0, sB1);
                acc_fp8(u2, sB0, sB1); acc_fp8(u3, sB0, sB1);
            }
            for (; iB + 4 < eB; iB += 8) {
                int b0 = srcs[iB], b1 = srcs[iB + 4];
                unsigned u0 = h2f8[(size_t)b0 * 16 + t];
                unsigned u1 = h2f8[(size_t)b1 * 16 + t];
                acc_fp8(u0, sB0, sB1); acc_fp8(u1, sB0, sB1);
            }
            if (iB < eB) {
                unsigned u0 = h2f8[(size_t)srcs[iB] * 16 + t];
                acc_fp8(u0, sB0, sB1);
            }
        }
        float axA = sA0.x, ayA = sA0.y, azA = sA1.x, awA = sA1.y;
        float axB = sB0.x, ayB = sB0.y, azB = sB1.x, awB = sB1.y;
        axA += __shfl_xor(axA, 16, 64); ayA += __shfl_xor(ayA, 16, 64);
        azA += __shfl_xor(azA, 16, 64); awA += __shfl_xor(awA, 16, 64);
        axA += __shfl_xor(axA, 32, 64); ayA += __shfl_xor(ayA, 32, 64);
        azA += __shfl_xor(azA, 32, 64); awA += __shfl_xor(awA, 32, 64);
        axB += __shfl_xor(axB, 16, 64); ayB += __shfl_xor(ayB, 16, 64);
        azB += __shfl_xor(azB, 16, 64); awB += __shfl_xor(awB, 16, 64);
        axB += __shfl_xor(axB, 32, 64); ayB += __shfl_xor(ayB, 32, 64);
        azB += __shfl_xor(azB, 32, 64); awB += __shfl_xor(awB, 32, 64);
        if (q == 0 && t < 10) {
            float rd = 1.0f / fmaxf((float)odA.y, 1.0f);
            float4 o = *(float4*)&out[(size_t)n0 * NCLS + t * 4];  // op
            o.x = fmaf(axA, rd, o.x); o.y = fmaf(ayA, rd, o.y);
            o.z = fmaf(azA, rd, o.z); o.w = fmaf(awA, rd, o.w);
            *(float4*)&out[(size_t)n0 * NCLS + t * 4] = o;
            if (hasB) {
                float rdB = 1.0f / fmaxf((float)odB.y, 1.0f);
                float4 oB = *(float4*)&out[(size_t)n1 * NCLS + t * 4];
                oB.x = fmaf(axB, rdB, oB.x); oB.y = fmaf(ayB, rdB, oB.y);
                oB.z = fmaf(azB, rdB, oB.z); oB.w = fmaf(awB, rdB, oB.w);
                *(float4*)&out[(size_t)n1 * NCLS + t * 4] = oB;
            }
        }
    }
}

extern "C" void kernel_launch(void* const* d_in, const int* in_sizes, int n_in,
                              void* d_out, int out_size, void* d_ws, size_t ws_size,
                              hipStream_t stream) {
    const float* x   = (const float*)d_in[0];
    const int*   ei  = (const int*)d_in[1];   // [2, E] int32
    const float* W1l = (const float*)d_in[2];
    const float* b1  = (const float*)d_in[3];
    const float* W1r = (const float*)d_in[4];
    const float* W2l = (const float*)d_in[5];
    const float* b2  = (const float*)d_in[6];
    const float* W2r = (const float*)d_in[7];
    float* out = (float*)d_out;

    const int* srcv = ei;
    const int* dstv = ei + N_EDGES;

    // ws: bcur 508 | gcnt 1 | offdeg 2N | bedges NBIN*BINCAP | srcs E
    //     | aggb 64N u16 | xb 64N u16 | h2f8 16N u32 (64B-aligned rows)
    int* bcur   = (int*)d_ws;              // 508 ints for bins
    int* gcnt   = bcur + 508;              // 1 int (zeroed with bcur)
    uint2* offdeg = (uint2*)(bcur + 512);
    int* bedges = (int*)(offdeg + N_NODES);
    int* srcs   = bedges + (size_t)NBIN * BINCAP;
    unsigned short* aggb = (unsigned short*)(srcs + N_EDGES);
    unsigned short* xb   = aggb + (size_t)64 * N_NODES;
    unsigned int*   h2f8 = (unsigned int*)(xb + (size_t)64 * N_NODES);

    hipMemsetAsync(bcur, 0, 512 * sizeof(int), stream);
    k_bucket<<<BKBLK, BKTHR, 0, stream>>>(srcv, dstv, bcur, bedges);
    k_xb<<<2048, 256, 0, stream>>>(x, (unsigned int*)xb);
    k_csrfill<<<NBIN, 256, 0, stream>>>(bcur, bedges, gcnt, offdeg, srcs);
    k_agg<<<2048, 256, 0, stream>>>(offdeg, srcs, xb, aggb);
    k_dense<<<768, 256, 0, stream>>>(aggb, xb, W1l, b1, W1r, W2l, b2, W2r, h2f8, out);
    k_out<<<2048, 256, 0, stream>>>(offdeg, srcs, h2f8, out);
}

// Round 3
// 148.823 us; speedup vs baseline: 1.1614x; 1.1114x over previous
//
#include <hip/hip_runtime.h>

#define N_NODES 100000
#define N_EDGES 1600000
#define NCLS 40
#define BIN_SH 8
#define BIN_N 256                      // nodes per bin == block size
#define NBIN ((N_NODES + BIN_N - 1) / BIN_N)   // 391
#define BINCAP 4800                    // per-bin capacity (mean 4092 + ~11 sigma)
#define BKBLK 256                      // k_bucket blocks (1 per CU)
#define BKTHR 1024                     // k_bucket threads (16 waves/CU)
#define CHUNK (N_EDGES / BKBLK)        // 6250 edges per block
#define SENTINEL N_NODES               // pad index -> all-zero feature row

typedef __attribute__((ext_vector_type(8))) short s8v;   // 8 bf16 (4 VGPRs)
typedef __attribute__((ext_vector_type(4))) float f4v;   // MFMA C/D

__device__ __forceinline__ unsigned short f2bf(float f) {
    union { float f; unsigned int u; } v; v.f = f;
    unsigned int u = v.u + 0x7FFFu + ((v.u >> 16) & 1u);   // RNE
    return (unsigned short)(u >> 16);
}
__device__ __forceinline__ float blo(unsigned int u) {
    union { unsigned int u; float f; } v; v.u = u << 16; return v.f;
}
__device__ __forceinline__ float bhi(unsigned int u) {
    union { unsigned int u; float f; } v; v.u = u & 0xFFFF0000u; return v.f;
}

// ---------------- fp8 e4m3 encode/decode (HW builtins, soft fallback) -------
#if __has_builtin(__builtin_amdgcn_cvt_pk_fp8_f32) && __has_builtin(__builtin_amdgcn_cvt_f32_fp8)
#define FP8_HW 1
#else
#define FP8_HW 0
#endif

__device__ __forceinline__ unsigned char enc_e4m3_sw(float f) {
    union { float f; unsigned int u; } v; v.f = f;
    unsigned int s = (v.u >> 24) & 0x80u;
    float af = fabsf(f);
    if (af >= 448.0f) return (unsigned char)(s | 0x7E);
    if (af < 0.015625f) {
        int q = (int)rintf(af * 512.0f);
        return (unsigned char)(s | (q & 7));
    }
    unsigned int n = v.u & 0x7FFFFFFFu;
    n = n + 0x7FFFFu + ((n >> 20) & 1u);
    int e = (int)(n >> 23) - 120;
    unsigned int m = (n >> 20) & 7u;
    if (e <= 0) { int q = (int)rintf(af * 512.0f); return (unsigned char)(s | (q & 7)); }
    if (e > 15) return (unsigned char)(s | 0x7E);
    return (unsigned char)(s | (e << 3) | m);
}
__device__ __forceinline__ float dec_e4m3_sw(unsigned int byte) {
    unsigned int sgn = byte >> 7, e = (byte >> 3) & 15u, m = byte & 7u;
    float mag;
    if (e) { union { unsigned int u; float f; } v; v.u = ((e + 120u) << 23) | (m << 20); mag = v.f; }
    else mag = (float)m * 0.001953125f;
    return sgn ? -mag : mag;
}

__device__ __forceinline__ unsigned int pack4_fp8(float a, float b, float c, float d) {
#if FP8_HW
    unsigned int w = __builtin_amdgcn_cvt_pk_fp8_f32(a, b, 0u, false);
    w = __builtin_amdgcn_cvt_pk_fp8_f32(c, d, w, true);
    return w;
#else
    return (unsigned int)enc_e4m3_sw(a) | ((unsigned int)enc_e4m3_sw(b) << 8) |
           ((unsigned int)enc_e4m3_sw(c) << 16) | ((unsigned int)enc_e4m3_sw(d) << 24);
#endif
}
__device__ __forceinline__ void unpack4_fp8(unsigned int w, float& a, float& b, float& c, float& d) {
#if FP8_HW
    a = __builtin_amdgcn_cvt_f32_fp8(w, 0);
    b = __builtin_amdgcn_cvt_f32_fp8(w, 1);
    c = __builtin_amdgcn_cvt_f32_fp8(w, 2);
    d = __builtin_amdgcn_cvt_f32_fp8(w, 3);
#else
    a = dec_e4m3_sw(w & 255u); b = dec_e4m3_sw((w >> 8) & 255u);
    c = dec_e4m3_sw((w >> 16) & 255u); d = dec_e4m3_sw(w >> 24);
#endif
}

// ---------------- block-chunked bucketing into 391 x 256-node bins ----------
__global__ __launch_bounds__(BKTHR) void k_bucket(
        const int* __restrict__ srcv, const int* __restrict__ dstv,
        int* __restrict__ bcur, int* __restrict__ bedges) {
    __shared__ int cnt4[4][NBIN];
    __shared__ int base[NBIN], lcur[NBIN];
    for (int i = threadIdx.x; i < 4 * NBIN; i += BKTHR) cnt4[i / NBIN][i % NBIN] = 0;
    __syncthreads();
    const int grp = threadIdx.x >> 8;
    const int beg = blockIdx.x * CHUNK;
    const int end = beg + CHUNK;
    for (int e = beg + threadIdx.x; e < end; e += BKTHR) {
        int d = dstv[e]; d = min(max(d, 0), N_NODES - 1);
        atomicAdd(&cnt4[grp][d >> BIN_SH], 1);
    }
    __syncthreads();
    for (int i = threadIdx.x; i < NBIN; i += BKTHR) {
        int c = cnt4[0][i] + cnt4[1][i] + cnt4[2][i] + cnt4[3][i];
        base[i] = atomicAdd(&bcur[i], c);
        lcur[i] = 0;
    }
    __syncthreads();
    for (int e = beg + threadIdx.x; e < end; e += BKTHR) {
        int d = dstv[e]; d = min(max(d, 0), N_NODES - 1);
        int s = srcv[e]; s = min(max(s, 0), N_NODES - 1);
        int b = d >> BIN_SH;
        int slot = atomicAdd(&lcur[b], 1) + base[b];
        if (slot < BINCAP) bedges[b * BINCAP + slot] = ((d & (BIN_N - 1)) << 17) | s;
    }
}

// ---------------- fused CSR: histogram + scan + base-claim + fill -----------
// Each node's region is padded to a multiple of 4 slots; pads hold SENTINEL
// (zero row). Region starts are therefore 16B-aligned -> int4 srcs loads.
__global__ __launch_bounds__(256) void k_csrfill(
        const int* __restrict__ bcur, const int* __restrict__ bedges,
        int* __restrict__ gcnt, uint2* __restrict__ offdeg,
        int* __restrict__ srcs) {
    __shared__ int dcnt[BIN_N];
    __shared__ int s[BIN_N];
    __shared__ int base_s;
    const int b = blockIdx.x;
    dcnt[threadIdx.x] = 0;
    __syncthreads();
    const int cnt = min(bcur[b], BINCAP);
    for (int e = threadIdx.x; e < cnt; e += 256)
        atomicAdd(&dcnt[bedges[b * BINCAP + e] >> 17], 1);
    __syncthreads();
    int v = dcnt[threadIdx.x];
    int pv = (v + 3) & ~3;                 // padded degree (multiple of 4)
    s[threadIdx.x] = pv;
    __syncthreads();
    int acc = pv;
    for (int off = 1; off < 256; off <<= 1) {
        int t = (threadIdx.x >= off) ? s[threadIdx.x - off] : 0;
        __syncthreads();
        acc += t;
        s[threadIdx.x] = acc;
        __syncthreads();
    }
    if (threadIdx.x == 255) base_s = atomicAdd(gcnt, acc);  // acc == padded bin total (mult of 4)
    __syncthreads();
    const int gbeg = (acc - pv) + base_s;  // multiple of 4 -> 16B-aligned
    const int node = (b << BIN_SH) + threadIdx.x;
    if (node < N_NODES) offdeg[node] = make_uint2((unsigned)gbeg, (unsigned)v);
    // reuse LDS: s -> per-node global base, dcnt -> cursor
    s[threadIdx.x] = gbeg;
    dcnt[threadIdx.x] = 0;
    __syncthreads();
    for (int e = threadIdx.x; e < cnt; e += 256) {
        int val = bedges[b * BINCAP + e];
        int dl = val >> 17;
        int sv = val & 0x1FFFF;
        int slot = atomicAdd(&dcnt[dl], 1);
        srcs[s[dl] + slot] = sv;
    }
    // sentinel-fill the pad slots [v, pv) of this thread's node
    for (int p = v; p < pv; ++p) srcs[gbeg + p] = SENTINEL;
}

// ---------------- x f32 -> bf16 cast + zero sentinel rows ----------------
__global__ void k_xb(const float* __restrict__ x, unsigned int* __restrict__ xb,
                     unsigned int* __restrict__ h2f8) {
    int i = blockIdx.x * blockDim.x + threadIdx.x;
    int stride = gridDim.x * blockDim.x;
    const int total = N_NODES * 64 / 8;
    for (int t = i; t < total; t += stride) {
        float4 v0 = ((const float4*)x)[t * 2];
        float4 v1 = ((const float4*)x)[t * 2 + 1];
        uint4 o;
        o.x = (unsigned)f2bf(v0.x) | ((unsigned)f2bf(v0.y) << 16);
        o.y = (unsigned)f2bf(v0.z) | ((unsigned)f2bf(v0.w) << 16);
        o.z = (unsigned)f2bf(v1.x) | ((unsigned)f2bf(v1.y) << 16);
        o.w = (unsigned)f2bf(v1.z) | ((unsigned)f2bf(v1.w) << 16);
        ((uint4*)xb)[t] = o;
    }
    // zero-row sentinels: xb row N_NODES (8 uint4), h2f8 row N_NODES (4 uint4)
    uint4 z; z.x = 0u; z.y = 0u; z.z = 0u; z.w = 0u;
    if (i < 8)  ((uint4*)xb)[(size_t)N_NODES * 8 + i] = z;
    if (i >= 8 && i < 12) ((uint4*)h2f8)[(size_t)N_NODES * 4 + (i - 8)] = z;
}

// ---------------- gather-mean (bf16 in / bf16 out) --------------------------
// Chain q owns 16B-aligned blocks j==q (mod 4): one int4 srcs load -> 4 gather
// addresses; next block's int4 is prefetched so srcs latency is off the
// critical path. Pads gather the zero row (no drain code).
__global__ __launch_bounds__(256) void k_agg(
        const uint2* __restrict__ offdeg, const int* __restrict__ srcs,
        const unsigned short* __restrict__ xb, unsigned short* __restrict__ aggb) {
    const int w = threadIdx.x >> 6;
    const int q = (threadIdx.x >> 4) & 3;
    const int t = threadIdx.x & 15;
    for (int node = blockIdx.x * 4 + w; node < N_NODES; node += gridDim.x * 4) {
        uint2 od = offdeg[node];
        const int beg = (int)od.x;
        const int m = ((int)od.y + 3) >> 2;    // number of 4-slot blocks
        float ax = 0.0f, ay = 0.0f, az = 0.0f, aw = 0.0f;
        int j = q;
        if (j < m) {
            int4 sv = *(const int4*)&srcs[beg + 4 * j];
            while (true) {
                const int4 cur = sv;
                const int jn = j + 4;
                if (jn < m) sv = *(const int4*)&srcs[beg + 4 * jn];   // prefetch
                uint2 u0 = *(const uint2*)&xb[(size_t)cur.x * 64 + t * 4];
                uint2 u1 = *(const uint2*)&xb[(size_t)cur.y * 64 + t * 4];
                uint2 u2 = *(const uint2*)&xb[(size_t)cur.z * 64 + t * 4];
                uint2 u3 = *(const uint2*)&xb[(size_t)cur.w * 64 + t * 4];
                ax += (blo(u0.x) + blo(u1.x)) + (blo(u2.x) + blo(u3.x));
                ay += (bhi(u0.x) + bhi(u1.x)) + (bhi(u2.x) + bhi(u3.x));
                az += (blo(u0.y) + blo(u1.y)) + (blo(u2.y) + blo(u3.y));
                aw += (bhi(u0.y) + bhi(u1.y)) + (bhi(u2.y) + bhi(u3.y));
                if (jn >= m) break;
                j = jn;
            }
        }
        ax += __shfl_xor(ax, 16, 64); ay += __shfl_xor(ay, 16, 64);
        az += __shfl_xor(az, 16, 64); aw += __shfl_xor(aw, 16, 64);
        ax += __shfl_xor(ax, 32, 64); ay += __shfl_xor(ay, 32, 64);
        az += __shfl_xor(az, 32, 64); aw += __shfl_xor(aw, 32, 64);
        if (q == 0) {
            float rd = 1.0f / fmaxf((float)od.y, 1.0f);
            uint2 r;
            r.x = (unsigned)f2bf(ax * rd) | ((unsigned)f2bf(ay * rd) << 16);
            r.y = (unsigned)f2bf(az * rd) | ((unsigned)f2bf(aw * rd) << 16);
            *(uint2*)&aggb[(size_t)node * 64 + t * 4] = r;
        }
    }
}

// ---------------- fused dense via MFMA; h2 stored fp8 (64B-aligned rows) ----
__global__ __launch_bounds__(256) void k_dense(
        const unsigned short* __restrict__ aggb, const unsigned short* __restrict__ xb,
        const float* __restrict__ W1l, const float* __restrict__ b1,
        const float* __restrict__ W1r,
        const float* __restrict__ W2l, const float* __restrict__ b2,
        const float* __restrict__ W2r,
        unsigned int* __restrict__ h2f8, float* __restrict__ op) {
    __shared__ __align__(16) unsigned short wl1[64][72], wr1[64][72];
    __shared__ __align__(16) unsigned short wl2[48][72], wr2[48][72];
    __shared__ __align__(16) unsigned short hsm[4][16][72];
    for (int idx = threadIdx.x; idx < 64 * 64; idx += 256) {
        int f = idx >> 6, k = idx & 63;
        wl1[f][k] = f2bf(W1l[idx]);
        wr1[f][k] = f2bf(W1r[idx]);
    }
    for (int idx = threadIdx.x; idx < 48 * 64; idx += 256) {
        int c = idx >> 6, k = idx & 63;
        wl2[c][k] = (c < NCLS) ? f2bf(W2l[c * 64 + k]) : (unsigned short)0;
        wr2[c][k] = (c < NCLS) ? f2bf(W2r[c * 64 + k]) : (unsigned short)0;
    }
    __syncthreads();
    const int w   = threadIdx.x >> 6;
    const int l15 = threadIdx.x & 15;
    const int g   = (threadIdx.x >> 4) & 3;
    float b1v[4][4], b2v[3][4];
    #pragma unroll
    for (int ft = 0; ft < 4; ++ft)
        #pragma unroll
        for (int r = 0; r < 4; ++r)
            b1v[ft][r] = b1[16 * ft + 4 * g + r];
    #pragma unroll
    for (int ct = 0; ct < 3; ++ct)
        #pragma unroll
        for (int r = 0; r < 4; ++r) {
            int c = 16 * ct + 4 * g + r;
            b2v[ct][r] = (c < NCLS) ? b2[c] : 0.0f;
        }
    unsigned short* hs = &hsm[w][0][0];
    const int gw = blockIdx.x * 4 + w;
    const int nw = gridDim.x * 4;
    for (int tile = gw; tile < N_NODES / 16; tile += nw) {
        const size_t node = (size_t)tile * 16 + l15;
        s8v aB0 = *(const s8v*)&aggb[node * 64 + 8 * g];
        s8v aB1 = *(const s8v*)&aggb[node * 64 + 32 + 8 * g];
        s8v xB0 = *(const s8v*)&xb[node * 64 + 8 * g];
        s8v xB1 = *(const s8v*)&xb[node * 64 + 32 + 8 * g];
        #pragma unroll
        for (int ft = 0; ft < 4; ++ft) {
            f4v c;
            c[0] = b1v[ft][0]; c[1] = b1v[ft][1]; c[2] = b1v[ft][2]; c[3] = b1v[ft][3];
            const size_t rb = (size_t)(16 * ft + l15) * 144 + 16 * g;
            s8v A0 = *(const s8v*)((const char*)wl1 + rb);
            s8v A1 = *(const s8v*)((const char*)wl1 + rb + 64);
            s8v R0 = *(const s8v*)((const char*)wr1 + rb);
            s8v R1 = *(const s8v*)((const char*)wr1 + rb + 64);
            c = __builtin_amdgcn_mfma_f32_16x16x32_bf16(A0, aB0, c, 0, 0, 0);
            c = __builtin_amdgcn_mfma_f32_16x16x32_bf16(A1, aB1, c, 0, 0, 0);
            c = __builtin_amdgcn_mfma_f32_16x16x32_bf16(R0, xB0, c, 0, 0, 0);
            c = __builtin_amdgcn_mfma_f32_16x16x32_bf16(R1, xB1, c, 0, 0, 0);
            uint2 u;
            u.x = (unsigned)f2bf(fmaxf(c[0], 0.0f)) | ((unsigned)f2bf(fmaxf(c[1], 0.0f)) << 16);
            u.y = (unsigned)f2bf(fmaxf(c[2], 0.0f)) | ((unsigned)f2bf(fmaxf(c[3], 0.0f)) << 16);
            *(uint2*)((char*)hs + l15 * 144 + 32 * ft + 8 * g) = u;
        }
        s8v hB0 = *(const s8v*)((const char*)hs + l15 * 144 + 16 * g);
        s8v hB1 = *(const s8v*)((const char*)hs + l15 * 144 + 64 + 16 * g);
        #pragma unroll
        for (int ct = 0; ct < 3; ++ct) {
            f4v p; p[0] = 0.0f; p[1] = 0.0f; p[2] = 0.0f; p[3] = 0.0f;
            f4v qv;
            qv[0] = b2v[ct][0]; qv[1] = b2v[ct][1]; qv[2] = b2v[ct][2]; qv[3] = b2v[ct][3];
            const size_t rb = (size_t)(16 * ct + l15) * 144 + 16 * g;
            s8v L0 = *(const s8v*)((const char*)wl2 + rb);
            s8v L1 = *(const s8v*)((const char*)wl2 + rb + 64);
            s8v Q0 = *(const s8v*)((const char*)wr2 + rb);
            s8v Q1 = *(const s8v*)((const char*)wr2 + rb + 64);
            p  = __builtin_amdgcn_mfma_f32_16x16x32_bf16(L0, hB0, p, 0, 0, 0);
            p  = __builtin_amdgcn_mfma_f32_16x16x32_bf16(L1, hB1, p, 0, 0, 0);
            qv = __builtin_amdgcn_mfma_f32_16x16x32_bf16(Q0, hB0, qv, 0, 0, 0);
            qv = __builtin_amdgcn_mfma_f32_16x16x32_bf16(Q1, hB1, qv, 0, 0, 0);
            int c0 = 16 * ct + 4 * g;
            if (c0 < NCLS) {
                h2f8[node * 16 + (c0 >> 2)] = pack4_fp8(p[0], p[1], p[2], p[3]);
                float4 o; o.x = qv[0]; o.y = qv[1]; o.z = qv[2]; o.w = qv[3];
                *(float4*)&op[node * NCLS + c0] = o;
            }
        }
    }
}

// ---------------- layer-2 gather: out = mean(fp8 h2[src]) + op --------------
// Same int4-block chain structure as k_agg.
__global__ __launch_bounds__(256) void k_out(
        const uint2* __restrict__ offdeg, const int* __restrict__ srcs,
        const unsigned int* __restrict__ h2f8, float* __restrict__ out) {
    const int w = threadIdx.x >> 6;
    const int q = (threadIdx.x >> 4) & 3;
    const int t = threadIdx.x & 15;
    for (int node = blockIdx.x * 4 + w; node < N_NODES; node += gridDim.x * 4) {
        uint2 od = offdeg[node];
        const int beg = (int)od.x;
        const int m = ((int)od.y + 3) >> 2;
        float ax = 0.0f, ay = 0.0f, az = 0.0f, aw = 0.0f;
        if (t < 10) {
            int j = q;
            if (j < m) {
                int4 sv = *(const int4*)&srcs[beg + 4 * j];
                while (true) {
                    const int4 cur = sv;
                    const int jn = j + 4;
                    if (jn < m) sv = *(const int4*)&srcs[beg + 4 * jn];   // prefetch
                    unsigned u0 = h2f8[(size_t)cur.x * 16 + t];
                    unsigned u1 = h2f8[(size_t)cur.y * 16 + t];
                    unsigned u2 = h2f8[(size_t)cur.z * 16 + t];
                    unsigned u3 = h2f8[(size_t)cur.w * 16 + t];
                    float a0, b0, c0, d0, a1, b1, c1, d1;
                    float a2, b2, c2, d2, a3, b3, c3, d3;
                    unpack4_fp8(u0, a0, b0, c0, d0);
                    unpack4_fp8(u1, a1, b1, c1, d1);
                    unpack4_fp8(u2, a2, b2, c2, d2);
                    unpack4_fp8(u3, a3, b3, c3, d3);
                    ax += (a0 + a1) + (a2 + a3); ay += (b0 + b1) + (b2 + b3);
                    az += (c0 + c1) + (c2 + c3); aw += (d0 + d1) + (d2 + d3);
                    if (jn >= m) break;
                    j = jn;
                }
            }
        }
        ax += __shfl_xor(ax, 16, 64); ay += __shfl_xor(ay, 16, 64);
        az += __shfl_xor(az, 16, 64); aw += __shfl_xor(aw, 16, 64);
        ax += __shfl_xor(ax, 32, 64); ay += __shfl_xor(ay, 32, 64);
        az += __shfl_xor(az, 32, 64); aw += __shfl_xor(aw, 32, 64);
        if (q == 0 && t < 10) {
            float rd = 1.0f / fmaxf((float)od.y, 1.0f);
            float4 o = *(float4*)&out[(size_t)node * NCLS + t * 4];  // op
            o.x = fmaf(ax, rd, o.x); o.y = fmaf(ay, rd, o.y);
            o.z = fmaf(az, rd, o.z); o.w = fmaf(aw, rd, o.w);
            *(float4*)&out[(size_t)node * NCLS + t * 4] = o;
        }
    }
}

extern "C" void kernel_launch(void* const* d_in, const int* in_sizes, int n_in,
                              void* d_out, int out_size, void* d_ws, size_t ws_size,
                              hipStream_t stream) {
    const float* x   = (const float*)d_in[0];
    const int*   ei  = (const int*)d_in[1];   // [2, E] int32
    const float* W1l = (const float*)d_in[2];
    const float* b1  = (const float*)d_in[3];
    const float* W1r = (const float*)d_in[4];
    const float* W2l = (const float*)d_in[5];
    const float* b2  = (const float*)d_in[6];
    const float* W2r = (const float*)d_in[7];
    float* out = (float*)d_out;

    const int* srcv = ei;
    const int* dstv = ei + N_EDGES;

    // ws: bcur 508 | gcnt 1 | offdeg 2N | bedges NBIN*BINCAP
    //     | srcs E+3N+16 (padded CSR) | aggb 64N u16
    //     | xb 64(N+1) u16 (zero sentinel row) | h2f8 16(N+1) u32
    int* bcur   = (int*)d_ws;              // 508 ints for bins
    int* gcnt   = bcur + 508;              // 1 int (zeroed with bcur)
    uint2* offdeg = (uint2*)(bcur + 512);
    int* bedges = (int*)(offdeg + N_NODES);
    int* srcs   = bedges + (size_t)NBIN * BINCAP;
    unsigned short* aggb = (unsigned short*)(srcs + (size_t)N_EDGES + 3 * N_NODES + 16);
    unsigned short* xb   = aggb + (size_t)64 * N_NODES;
    unsigned int*   h2f8 = (unsigned int*)(xb + (size_t)64 * (N_NODES + 1));

    hipMemsetAsync(bcur, 0, 512 * sizeof(int), stream);
    k_bucket<<<BKBLK, BKTHR, 0, stream>>>(srcv, dstv, bcur, bedges);
    k_xb<<<2048, 256, 0, stream>>>(x, (unsigned int*)xb, h2f8);
    k_csrfill<<<NBIN, 256, 0, stream>>>(bcur, bedges, gcnt, offdeg, srcs);
    k_agg<<<2048, 256, 0, stream>>>(offdeg, srcs, xb, aggb);
    k_dense<<<768, 256, 0, stream>>>(aggb, xb, W1l, b1, W1r, W2l, b2, W2r, h2f8, out);
    k_out<<<2048, 256, 0, stream>>>(offdeg, srcs, h2f8, out);
}